// Round 6
// baseline (685.040 us; speedup 1.0000x reference)
//
#include <hip/hip_runtime.h>

// Longformer sliding-chunks no-overlap attention. b=2, s=8192, h=8, d=64, W=256.
// Two-kernel scheme (ws >= 50.3MB, else fallback to proven R4 kernel):
//   prep:  K -> Kh,Kl bf16 Markidis split, layout (b,h,s,d)  [wave loads contiguous]
//          V -> Vt bf16, layout (b,h,p,d,64) 64-key panels   [wave loads contiguous]
//   main (4 blocks/CU): per (bb,cc,hh,32-row tile), 4 waves, wave owns 64-key slice.
//     QK:  S^T = K*Q^T via mfma_16x16x32_bf16 (KhQh+KhQl+KlQh), frags from global.
//     SM:  rows on lane&15 -> 2-step shfl + cross-wave LDS reduce.
//     att: b128 nontemporal stores.
//     PV:  O^T = V^T*P^T; V^T frags direct from global; P^T via wave-private LDS.
//     epi: cross-wave fp32 reduce through LDS.
// d_out: [output (b,s,h,64)][attention (b,s,h,768)], both f32.

#define SEQ  8192
#define NH   8
#define DM   64
#define WIN  256
#define NC   32

typedef float  f32x4  __attribute__((ext_vector_type(4)));
typedef short  bf16x8 __attribute__((ext_vector_type(8)));
typedef short  bf16x4 __attribute__((ext_vector_type(4)));
typedef unsigned short u16;

__device__ __forceinline__ u16 bf16_rne(float x) {
    unsigned u = __builtin_bit_cast(unsigned, x);
    u += 0x7FFFu + ((u >> 16) & 1u);
    return (u16)(u >> 16);
}
__device__ __forceinline__ float bf16_f32(u16 h) {
    unsigned u = ((unsigned)h) << 16;
    return __builtin_bit_cast(float, u);
}

// ---------------------------------------------------------------- prep kernel
__global__ __launch_bounds__(256)
void wattn_prep(const float* __restrict__ kg, const float* __restrict__ vg,
                u16* __restrict__ khp, u16* __restrict__ klp, u16* __restrict__ vtp)
{
    __shared__ float tile[64 * 68];   // V transpose staging (padded)
    const int bid = blockIdx.x;
    const int t   = threadIdx.x;

    if (bid < 4096) {
        // K: (b,s,h,d) f32 -> (b,h,s,d) bf16 hi/lo. Block = (bb,hh,32-row panel)
        int id = bid;
        const int sp = id & 255; id >>= 8;
        const int hh = id & 7;   id >>= 3;
        const int bb = id;
        const int r  = t >> 3;            // 0..31
        const int c  = (t & 7) * 8;
        const int s0 = sp * 32;
        const float* ip = kg + (((size_t)bb * SEQ + s0 + r) * NH + hh) * DM + c;
        f32x4 a0 = *(const f32x4*)ip;
        f32x4 a1 = *(const f32x4*)(ip + 4);
        bf16x8 h, l;
        #pragma unroll
        for (int i = 0; i < 8; ++i) {
            float f = (i < 4) ? a0[i] : a1[i - 4];
            u16 hv = bf16_rne(f);
            h[i] = (short)hv;
            l[i] = (short)bf16_rne(f - bf16_f32(hv));
        }
        const size_t ooff = (((size_t)bb * NH + hh) * SEQ + s0 + r) * DM + c;
        *(bf16x8*)(khp + ooff) = h;
        *(bf16x8*)(klp + ooff) = l;
    } else {
        // V: (b,s,h,d) f32 -> (b,h,p,d,64) bf16, 64-key panels
        int vid = bid - 4096;
        const int p  = vid & 127; vid >>= 7;
        const int hh = vid & 7;   vid >>= 3;
        const int bb = vid;
        const int s0 = p * 64;

        const int r  = t >> 2;            // 0..63
        const int dg = (t & 3) * 16;
        const float* vp = vg + (((size_t)bb * SEQ + s0 + r) * NH + hh) * DM + dg;
        #pragma unroll
        for (int i = 0; i < 4; ++i)
            *(f32x4*)&tile[r * 68 + dg + 4 * i] = *(const f32x4*)(vp + 4 * i);
        __syncthreads();

        const int d  = t >> 2;            // 0..63
        const int sg = (t & 3) * 16;
        u16* op = vtp + ((((size_t)bb * NH + hh) * 128 + p) * DM + d) * 64 + sg;
        bf16x8 o0, o1;
        #pragma unroll
        for (int j = 0; j < 8; ++j) o0[j] = (short)bf16_rne(tile[(sg + j) * 68 + d]);
        #pragma unroll
        for (int j = 0; j < 8; ++j) o1[j] = (short)bf16_rne(tile[(sg + 8 + j) * 68 + d]);
        *(bf16x8*)op       = o0;
        *(bf16x8*)(op + 8) = o1;
    }
}

// ---------------------------------------------------------------- main kernel
__global__ __launch_bounds__(256, 4)
void wattn_mfma3(const float* __restrict__ qg, const u16* __restrict__ khp,
                 const u16* __restrict__ klp, const u16* __restrict__ vtp,
                 float* __restrict__ outg, float* __restrict__ attng)
{
    // LDS: [0,34816) csc f32[4][32][68] (epilogue), overlays per-wave P
    //      pw (per wave) = u16[32][72] @ w*4608 bytes
    //      [34816,35328) smax f32[32][4]; [35328,35840) ssum
    __shared__ __align__(16) char lds[35840];

    const int t    = threadIdx.x;
    const int lane = t & 63;
    const int w    = t >> 6;
    const int a    = lane & 15;
    const int g4   = lane >> 4;

    u16*   pw   = (u16*)(lds) + w * 2304;
    float* csc  = (float*)lds;
    float* smax = (float*)(lds + 34816);
    float* ssum = smax + 128;

    int gid = blockIdx.x;
    gid = (gid & 7) * 512 + (gid >> 3);     // XCD swizzle (bijective, 4096=8*512)
    const int tile = gid & 7;  gid >>= 3;
    const int hh   = gid & 7;  gid >>= 3;
    const int cc   = gid & 31; gid >>= 5;
    const int bb   = gid;
    const int row0 = cc * WIN + tile * 32;

    // ---- Q^T B-fragments (hi/lo split in-kernel; each Q row used by 1 block) ----
    bf16x8 qh[2][2], ql[2][2];
    #pragma unroll
    for (int rt = 0; rt < 2; ++rt)
      #pragma unroll
      for (int ks = 0; ks < 2; ++ks) {
        const float* qp = qg + (((size_t)bb * SEQ + row0 + rt*16 + a) * NH + hh) * DM
                             + ks*32 + g4*8;
        f32x4 t0 = *(const f32x4*)qp;
        f32x4 t1 = *(const f32x4*)(qp + 4);
        #pragma unroll
        for (int i = 0; i < 8; ++i) {
            float f = (i < 4) ? t0[i] : t1[i - 4];
            u16 hv = bf16_rne(f);
            qh[rt][ks][i] = (short)hv;
            ql[rt][ks][i] = (short)bf16_rne(f - bf16_f32(hv));
        }
      }

    // ---- QK^T as S^T = K*Q^T: acc[e][ct][rt] (key=ct*16+g4*4+reg, row=rt*16+a)
    f32x4 acc[3][4][2];
    #pragma unroll
    for (int e = 0; e < 3; ++e)
      #pragma unroll
      for (int ct = 0; ct < 4; ++ct)
        #pragma unroll
        for (int rt = 0; rt < 2; ++rt)
            acc[e][ct][rt] = (f32x4){0.f, 0.f, 0.f, 0.f};

    #pragma unroll
    for (int e = 0; e < 3; ++e) {
        const int cs = cc + e - 1;
        if ((unsigned)cs < NC) {
            #pragma unroll
            for (int ct = 0; ct < 4; ++ct) {
                // (b,h,s,d): wave's 16 rows x 128B are contiguous
                const size_t koff = (((size_t)bb * NH + hh) * SEQ + cs*WIN + w*64 + ct*16 + a) * DM
                                  + g4*8;
                #pragma unroll
                for (int ks = 0; ks < 2; ++ks) {
                    bf16x8 kh = *(const bf16x8*)(khp + koff + ks*32);
                    bf16x8 kl = *(const bf16x8*)(klp + koff + ks*32);
                    #pragma unroll
                    for (int rt = 0; rt < 2; ++rt) {
                        acc[e][ct][rt] = __builtin_amdgcn_mfma_f32_16x16x32_bf16(kh, qh[rt][ks], acc[e][ct][rt], 0, 0, 0);
                        acc[e][ct][rt] = __builtin_amdgcn_mfma_f32_16x16x32_bf16(kh, ql[rt][ks], acc[e][ct][rt], 0, 0, 0);
                        acc[e][ct][rt] = __builtin_amdgcn_mfma_f32_16x16x32_bf16(kl, qh[rt][ks], acc[e][ct][rt], 0, 0, 0);
                    }
                }
            }
        }
    }

    // ---- softmax over 768 (row = rt*16 + a) ----
    float INV[2];
    #pragma unroll
    for (int rt = 0; rt < 2; ++rt) {
        float mm = 0.f;   // padded slots contribute score 0 (shift-safe: |s|<~50)
        #pragma unroll
        for (int e = 0; e < 3; ++e)
          #pragma unroll
          for (int ct = 0; ct < 4; ++ct)
            #pragma unroll
            for (int reg = 0; reg < 4; ++reg)
              mm = fmaxf(mm, acc[e][ct][rt][reg]);
        mm = fmaxf(mm, __shfl_xor(mm, 16));
        mm = fmaxf(mm, __shfl_xor(mm, 32));
        if (g4 == 0) smax[(rt*16 + a)*4 + w] = mm;
    }
    __syncthreads();
    #pragma unroll
    for (int rt = 0; rt < 2; ++rt) {
        const float* sp = smax + (rt*16 + a)*4;
        float mm = fmaxf(fmaxf(sp[0], sp[1]), fmaxf(sp[2], sp[3]));
        float s = 0.f;
        #pragma unroll
        for (int e = 0; e < 3; ++e)
          #pragma unroll
          for (int ct = 0; ct < 4; ++ct)
            #pragma unroll
            for (int reg = 0; reg < 4; ++reg) {
                float p = __expf(acc[e][ct][rt][reg] - mm);
                acc[e][ct][rt][reg] = p;
                s += p;
            }
        s += __shfl_xor(s, 16);
        s += __shfl_xor(s, 32);
        if (g4 == 0) ssum[(rt*16 + a)*4 + w] = s;
    }
    __syncthreads();
    #pragma unroll
    for (int rt = 0; rt < 2; ++rt) {
        const float* sp = ssum + (rt*16 + a)*4;
        INV[rt] = 1.0f / (sp[0] + sp[1] + sp[2] + sp[3]);
    }

    // ---- scale to probs + attention store (b128 nontemporal) ----
    #pragma unroll
    for (int rt = 0; rt < 2; ++rt) {
        float* ab = attng + (((size_t)bb * SEQ + row0 + rt*16 + a) * NH + hh) * 768
                          + w*64 + g4*4;
        #pragma unroll
        for (int e = 0; e < 3; ++e)
          #pragma unroll
          for (int ct = 0; ct < 4; ++ct) {
            f32x4 p = acc[e][ct][rt] * INV[rt];
            acc[e][ct][rt] = p;
            __builtin_nontemporal_store(p, (f32x4*)(ab + e*256 + ct*16));
          }
    }

    // ---- PV: O^T = V^T * P^T ----
    f32x4 acc2[4][2];
    #pragma unroll
    for (int dt = 0; dt < 4; ++dt)
      #pragma unroll
      for (int rt = 0; rt < 2; ++rt)
        acc2[dt][rt] = (f32x4){0.f, 0.f, 0.f, 0.f};

    #pragma unroll
    for (int e = 0; e < 3; ++e) {
        const int cs = cc + e - 1;
        if ((unsigned)cs < NC) {
            // stage P bf16 [row=rt*16+a][key], stride 72 (b64 writes, wave-private)
            #pragma unroll
            for (int rt = 0; rt < 2; ++rt)
              #pragma unroll
              for (int ct = 0; ct < 4; ++ct) {
                f32x4 p = acc[e][ct][rt];
                bf16x4 pk;
                #pragma unroll
                for (int reg = 0; reg < 4; ++reg) pk[reg] = (short)bf16_rne(p[reg]);
                *(bf16x4*)(pw + (rt*16 + a)*72 + ct*16 + g4*4) = pk;
              }
            #pragma unroll
            for (int ks = 0; ks < 2; ++ks) {
                bf16x8 pb[2], va[4];
                #pragma unroll
                for (int rt = 0; rt < 2; ++rt)
                    pb[rt] = *(const bf16x8*)(pw + (rt*16 + a)*72 + ks*32 + g4*8);
                #pragma unroll
                for (int dt = 0; dt < 4; ++dt)   // panel cs*4+w: contiguous 2KB/wave
                    va[dt] = *(const bf16x8*)(vtp
                        + ((((size_t)bb * NH + hh) * 128 + cs*4 + w) * DM + dt*16 + a) * 64
                        + ks*32 + g4*8);
                #pragma unroll
                for (int dt = 0; dt < 4; ++dt)
                  #pragma unroll
                  for (int rt = 0; rt < 2; ++rt)
                    acc2[dt][rt] = __builtin_amdgcn_mfma_f32_16x16x32_bf16(va[dt], pb[rt], acc2[dt][rt], 0, 0, 0);
            }
        }
    }

    // ---- cross-wave reduce + output ----
    __syncthreads();
    #pragma unroll
    for (int dt = 0; dt < 4; ++dt)
      #pragma unroll
      for (int rt = 0; rt < 2; ++rt)
        *(f32x4*)&csc[w*2176 + (rt*16 + a)*68 + dt*16 + g4*4] = acc2[dt][rt];
    __syncthreads();
    #pragma unroll
    for (int r = 0; r < 8; ++r) {
        const int row = w*8 + r;
        float s = csc[          row*68 + lane] + csc[  2176 + row*68 + lane]
                + csc[2*2176 + row*68 + lane] + csc[3*2176 + row*68 + lane];
        __builtin_nontemporal_store(
            s, outg + (((size_t)bb * SEQ + row0 + row) * NH + hh) * DM + lane);
    }
}

// ============================== fallback (proven R4 kernel, unchanged) =======
__global__ __launch_bounds__(256, 2)
void wattn_mfma(const float* __restrict__ qg, const float* __restrict__ kg,
                const float* __restrict__ vg, float* __restrict__ outg,
                float* __restrict__ attng)
{
    __shared__ __align__(16) char lds[50176];
    const int t    = threadIdx.x;
    const int lane = t & 63;
    const int w    = t >> 6;
    const int a    = lane & 15;
    const int g4   = lane >> 4;

    unsigned short* vtw = (unsigned short*)(lds)         + w * 4096;
    unsigned short* plw = (unsigned short*)(lds + 32768) + w * 2048;
    float* smax = (float*)(lds + 49152);
    float* ssum = smax + 128;
    float* csc  = (float*)lds;

    int gid = blockIdx.x;
    gid = (gid & 7) * 512 + (gid >> 3);
    const int tile = gid & 7;  gid >>= 3;
    const int hh   = gid & 7;  gid >>= 3;
    const int cc   = gid & 31; gid >>= 5;
    const int bb   = gid;
    const int row0 = cc * WIN + tile * 32;

    bf16x8 qh[2][2], ql[2][2];
    #pragma unroll
    for (int rt = 0; rt < 2; ++rt)
      #pragma unroll
      for (int ks = 0; ks < 2; ++ks) {
        const float* qp = qg + (((size_t)bb * SEQ + row0 + rt*16 + a) * NH + hh) * DM
                             + ks*32 + g4*8;
        f32x4 t0 = *(const f32x4*)qp;
        f32x4 t1 = *(const f32x4*)(qp + 4);
        float f[8];
        #pragma unroll
        for (int i = 0; i < 4; ++i) { f[i] = t0[i]; f[4+i] = t1[i]; }
        #pragma unroll
        for (int i = 0; i < 8; ++i) {
            unsigned short h = bf16_rne(f[i]);
            qh[rt][ks][i] = (short)h;
            ql[rt][ks][i] = (short)bf16_rne(f[i] - bf16_f32(h));
        }
      }

    f32x4 acc[3][2][4];
    #pragma unroll
    for (int e = 0; e < 3; ++e)
      #pragma unroll
      for (int rt = 0; rt < 2; ++rt)
        #pragma unroll
        for (int ct = 0; ct < 4; ++ct)
            acc[e][rt][ct] = (f32x4){0.f, 0.f, 0.f, 0.f};

    #pragma unroll
    for (int e = 0; e < 3; ++e) {
        const int cs = cc + e - 1;
        if ((unsigned)cs < NC) {
            #pragma unroll
            for (int ct = 0; ct < 4; ++ct) {
                const float* kp = kg + (((size_t)bb * SEQ + cs*WIN + w*64 + ct*16 + a) * NH + hh) * DM;
                #pragma unroll
                for (int ks = 0; ks < 2; ++ks) {
                    f32x4 t0 = *(const f32x4*)(kp + ks*32 + g4*8);
                    f32x4 t1 = *(const f32x4*)(kp + ks*32 + g4*8 + 4);
                    float f[8];
                    #pragma unroll
                    for (int i = 0; i < 4; ++i) { f[i] = t0[i]; f[4+i] = t1[i]; }
                    bf16x8 kh, kl;
                    #pragma unroll
                    for (int i = 0; i < 8; ++i) {
                        unsigned short h = bf16_rne(f[i]);
                        kh[i] = (short)h;
                        kl[i] = (short)bf16_rne(f[i] - bf16_f32(h));
                    }
                    #pragma unroll
                    for (int rt = 0; rt < 2; ++rt) {
                        acc[e][rt][ct] = __builtin_amdgcn_mfma_f32_16x16x32_bf16(qh[rt][ks], kh, acc[e][rt][ct], 0, 0, 0);
                        acc[e][rt][ct] = __builtin_amdgcn_mfma_f32_16x16x32_bf16(qh[rt][ks], kl, acc[e][rt][ct], 0, 0, 0);
                        acc[e][rt][ct] = __builtin_amdgcn_mfma_f32_16x16x32_bf16(ql[rt][ks], kh, acc[e][rt][ct], 0, 0, 0);
                    }
                }
            }
        }
    }

    float INV[2][4];
    #pragma unroll
    for (int rt = 0; rt < 2; ++rt)
      #pragma unroll
      for (int reg = 0; reg < 4; ++reg) {
        float mm = -3.4e38f;
        #pragma unroll
        for (int e = 0; e < 3; ++e)
          #pragma unroll
          for (int ct = 0; ct < 4; ++ct)
            mm = fmaxf(mm, acc[e][rt][ct][reg]);
        mm = fmaxf(mm, __shfl_xor(mm, 1));
        mm = fmaxf(mm, __shfl_xor(mm, 2));
        mm = fmaxf(mm, __shfl_xor(mm, 4));
        mm = fmaxf(mm, __shfl_xor(mm, 8));
        if (a == 0) smax[(rt*16 + g4*4 + reg)*4 + w] = mm;
      }
    __syncthreads();
    #pragma unroll
    for (int rt = 0; rt < 2; ++rt)
      #pragma unroll
      for (int reg = 0; reg < 4; ++reg) {
        const float* sp = smax + (rt*16 + g4*4 + reg)*4;
        float mm = fmaxf(fmaxf(sp[0], sp[1]), fmaxf(sp[2], sp[3]));
        float s = 0.f;
        #pragma unroll
        for (int e = 0; e < 3; ++e)
          #pragma unroll
          for (int ct = 0; ct < 4; ++ct) {
            float p = __expf(acc[e][rt][ct][reg] - mm);
            acc[e][rt][ct][reg] = p;
            s += p;
          }
        s += __shfl_xor(s, 1);
        s += __shfl_xor(s, 2);
        s += __shfl_xor(s, 4);
        s += __shfl_xor(s, 8);
        if (a == 0) ssum[(rt*16 + g4*4 + reg)*4 + w] = s;
      }
    __syncthreads();
    #pragma unroll
    for (int rt = 0; rt < 2; ++rt)
      #pragma unroll
      for (int reg = 0; reg < 4; ++reg) {
        const float* sp = ssum + (rt*16 + g4*4 + reg)*4;
        INV[rt][reg] = 1.0f / (sp[0] + sp[1] + sp[2] + sp[3]);
      }

    #pragma unroll
    for (int rt = 0; rt < 2; ++rt)
      #pragma unroll
      for (int reg = 0; reg < 4; ++reg) {
        const float iv = INV[rt][reg];
        float* ab = attng + (((size_t)bb * SEQ + row0 + rt*16 + g4*4 + reg) * NH + hh) * 768
                          + w*64 + a;
        #pragma unroll
        for (int e = 0; e < 3; ++e)
          #pragma unroll
          for (int ct = 0; ct < 4; ++ct) {
            float p = acc[e][rt][ct][reg] * iv;
            acc[e][rt][ct][reg] = p;
            __builtin_nontemporal_store(p, ab + e*256 + ct*16);
          }
      }

    f32x4 acc2[2][4];
    #pragma unroll
    for (int rt = 0; rt < 2; ++rt)
      #pragma unroll
      for (int dt = 0; dt < 4; ++dt)
        acc2[rt][dt] = (f32x4){0.f, 0.f, 0.f, 0.f};

    #pragma unroll
    for (int e = 0; e < 3; ++e) {
        const int cs = cc + e - 1;
        if ((unsigned)cs < NC) {
            __syncthreads();
            #pragma unroll
            for (int i = 0; i < 16; ++i) {
                const int kk = i*4 + g4;
                const float* vp = vg + (((size_t)bb * SEQ + cs*WIN + w*64 + kk) * NH + hh) * DM
                                     + a*4;
                f32x4 v4 = *(const f32x4*)vp;
                #pragma unroll
                for (int j = 0; j < 4; ++j) {
                    const int d = a*4 + j;
                    vtw[(d>>4)*1024 + (kk>>3)*128 + (d&15)*8 + (kk&7)] = bf16_rne(v4[j]);
                }
            }
            #pragma unroll
            for (int rt = 0; rt < 2; ++rt)
              #pragma unroll
              for (int reg = 0; reg < 4; ++reg) {
                const int prow = rt*16 + g4*4 + reg;
                #pragma unroll
                for (int ct = 0; ct < 4; ++ct) {
                    const int key = ct*16 + a;
                    plw[prow*64 + (((key>>3) ^ (prow&7)) << 3) + (key&7)] =
                        bf16_rne(acc[e][rt][ct][reg]);
                }
              }
            __syncthreads();
            #pragma unroll
            for (int ks = 0; ks < 2; ++ks) {
                bf16x8 pa[2], vb[4];
                #pragma unroll
                for (int rt = 0; rt < 2; ++rt) {
                    const int prow = rt*16 + a;
                    pa[rt] = *(const bf16x8*)(plw + prow*64 + ((((ks<<2) + g4) ^ (prow&7)) << 3));
                }
                #pragma unroll
                for (int dt = 0; dt < 4; ++dt)
                    vb[dt] = *(const bf16x8*)(vtw + dt*1024 + ((ks<<2) + g4)*128 + a*8);
                #pragma unroll
                for (int rt = 0; rt < 2; ++rt)
                  #pragma unroll
                  for (int dt = 0; dt < 4; ++dt)
                    acc2[rt][dt] = __builtin_amdgcn_mfma_f32_16x16x32_bf16(pa[rt], vb[dt], acc2[rt][dt], 0, 0, 0);
            }
        }
    }

    __syncthreads();
    #pragma unroll
    for (int rt = 0; rt < 2; ++rt)
      #pragma unroll
      for (int dt = 0; dt < 4; ++dt)
        #pragma unroll
        for (int reg = 0; reg < 4; ++reg)
          csc[w*2176 + (rt*16 + g4*4 + reg)*68 + dt*16 + a] = acc2[rt][dt][reg];
    __syncthreads();
    #pragma unroll
    for (int r = 0; r < 8; ++r) {
        const int row = w*8 + r;
        float s = csc[          row*68 + lane] + csc[  2176 + row*68 + lane]
                + csc[2*2176 + row*68 + lane] + csc[3*2176 + row*68 + lane];
        __builtin_nontemporal_store(
            s, outg + (((size_t)bb * SEQ + row0 + row) * NH + hh) * DM + lane);
    }
}

extern "C" void kernel_launch(void* const* d_in, const int* in_sizes, int n_in,
                              void* d_out, int out_size, void* d_ws, size_t ws_size,
                              hipStream_t stream) {
    const float* q = (const float*)d_in[0];
    const float* k = (const float*)d_in[1];
    const float* v = (const float*)d_in[2];

    float* out  = (float*)d_out;
    float* attn = (float*)d_out + (size_t)2 * SEQ * NH * DM;

    const size_t NELEM = (size_t)2 * SEQ * NH * DM;   // 8388608
    const size_t NEED  = 3 * NELEM * sizeof(u16);     // 50331648 B

    if (ws_size >= NEED) {
        u16* khp = (u16*)d_ws;
        u16* klp = khp + NELEM;
        u16* vtp = klp + NELEM;
        wattn_prep<<<dim3(6144), dim3(256), 0, stream>>>(k, v, khp, klp, vtp);
        wattn_mfma3<<<dim3(4096), dim3(256), 0, stream>>>(q, khp, klp, vtp, out, attn);
    } else {
        wattn_mfma<<<dim3(4096), dim3(256), 0, stream>>>(q, k, v, out, attn);
    }
}